// Round 10
// baseline (108.747 us; speedup 1.0000x reference)
//
#include <hip/hip_runtime.h>
#include <stdint.h>

// Problem: x0,y0 [B=64, C=36, L=4096] float32.
// out = y0 * (mean(x0,-1) + mean(y0,-1)), float32.
// Memory-bound: 113.2 MB minimal traffic -> ~18 us roofline at 6.3 TB/s.
//
// Harness note: dur_us carries ~83 us of workspace-poison fills
// (2 x 256 MiB fillBuffer @ ~41.5 us) inside the timed graph.
// Residual ladder: 4 indep waves 28 us; 9 waves/CU (no tail) 26 us;
// 36-requested waves/CU (32 resident + 1/8-occupancy tail round) 24 us.
//
// Round-9 theory: the 256-thread version runs 8 full rounds + a
// straggler round (256 blocks, 4 waves/CU) that is latency-bound ->
// ~+4 us makespan. Fix: ONE ROW PER 128-THREAD BLOCK (2 waves).
// 2304 blocks = 9 blocks/CU, ALL resident at once (18 waves/CU,
// under both the 32-wave and 16-block caps) -> single round, zero
// tail, 2x the occupancy of the round-2 no-tail version, and 16
// loads in flight per thread (8 f4 x + 8 f4 y).

typedef float v4f __attribute__((ext_vector_type(4)));

#define LL    4096
#define ROWS  (64 * 36)         // 2304 blocks, one per (b,c) row
#define BLOCK 128               // 2 waves; 9 blocks/CU all-resident
#define F4T   (LL / 4 / BLOCK)  // 8 float4 per thread

__global__ __launch_bounds__(BLOCK, 5) void spo2_rowscale(
    const float* __restrict__ x,
    const float* __restrict__ y,
    float* __restrict__ out)
{
    const int tid  = threadIdx.x;
    const size_t base = (size_t)blockIdx.x * LL;

    const v4f* xv = (const v4f*)(x + base);
    const v4f* yv = (const v4f*)(y + base);
    v4f*       ov = (v4f*)(out + base);

    // Issue ALL 16 loads before any dependent math (max MLP).
    v4f xr[F4T], yr[F4T];
#pragma unroll
    for (int i = 0; i < F4T; ++i) xr[i] = xv[tid + i * BLOCK];
#pragma unroll
    for (int i = 0; i < F4T; ++i) yr[i] = yv[tid + i * BLOCK];

    // 4 independent accumulators (short dep chains).
    float s0 = 0.f, s1 = 0.f, s2 = 0.f, s3 = 0.f;
#pragma unroll
    for (int i = 0; i < F4T; i += 2) {
        s0 += xr[i].x + xr[i].y + xr[i].z + xr[i].w;
        s1 += xr[i + 1].x + xr[i + 1].y + xr[i + 1].z + xr[i + 1].w;
        s2 += yr[i].x + yr[i].y + yr[i].z + yr[i].w;
        s3 += yr[i + 1].x + yr[i + 1].y + yr[i + 1].z + yr[i + 1].w;
    }
    float s = (s0 + s1) + (s2 + s3);

    // Wave-64 xor butterfly: all lanes end with the wave partial.
#pragma unroll
    for (int off = 32; off > 0; off >>= 1)
        s += __shfl_xor(s, off, 64);

    // 2-wave combine: 2 floats in LDS, one barrier, broadcast reads.
    __shared__ float rs[BLOCK / 64];
    const int wid  = tid >> 6;
    const int lane = tid & 63;
    if (lane == 0) rs[wid] = s;
    __syncthreads();

    const float total = rs[0] + rs[1];
    const float scale = total * (1.0f / (float)LL);

    // Nontemporal stores: out is never re-read, skip L2 allocation.
#pragma unroll
    for (int i = 0; i < F4T; ++i) {
        v4f o = yr[i] * scale;
        __builtin_nontemporal_store(o, ov + tid + i * BLOCK);
    }
}

extern "C" void kernel_launch(void* const* d_in, const int* in_sizes, int n_in,
                              void* d_out, int out_size, void* d_ws, size_t ws_size,
                              hipStream_t stream) {
    const float* x = (const float*)d_in[0];
    const float* y = (const float*)d_in[1];
    float* out = (float*)d_out;
    spo2_rowscale<<<ROWS, BLOCK, 0, stream>>>(x, y, out);
}